// Round 1
// baseline (931.938 us; speedup 1.0000x reference)
//
#include <hip/hip_runtime.h>
#include <hip/hip_bf16.h>
#include <stdint.h>

#define NBATCH 16
#define SEQ    2048
#define DMODEL 1024
#define TS     128     // output tile (M and N)
#define BK     64      // K-step (elements of the reduction dim per stage)
#define KSPLIT 8       // k-range split for the w^T x GEMV

typedef __attribute__((ext_vector_type(8))) short short8;   // 8 bf16 = 4 VGPRs
typedef __attribute__((ext_vector_type(4))) float f32x4;

// ---------------------------------------------------------------------------
// async global -> LDS, 16B per lane. LDS dest is wave-uniform base + lane*16.
__device__ __forceinline__ void gload16(const void* g, void* l) {
  __builtin_amdgcn_global_load_lds(
      (const __attribute__((address_space(1))) void*)g,
      (__attribute__((address_space(3))) void*)l, 16, 0, 0);
}

// Stage a [TS=128][BK=64] bf16 tile (16 KB) from row-major global (ld elems)
// into linear row-major LDS. 256 threads, 4 issues/thread.
__device__ __forceinline__ void stage_tile(const __hip_bfloat16* __restrict__ g,
                                           int ld, __hip_bfloat16* lds) {
  const int t = threadIdx.x;
  const int wave = t >> 6;
  const char* gb = (const char*)g;
  char* lb = (char*)lds + wave * 1024;   // wave-uniform; HW adds lane*16
#pragma unroll
  for (int it = 0; it < 4; ++it) {
    const int i   = it * 4096 + t * 16;  // linear byte in tile
    const int row = i >> 7;              // 128 B per row
    const int cb  = i & 127;
    gload16(gb + (size_t)row * (ld * 2) + cb, lb + it * 4096);
  }
}

// Accumulate C[128x128] (as 4 waves x 4x4 frags of 16x16) over NSTEP*BK of K.
// A: [128 rows][K] row-major, B: [128 rows][K] row-major (B^T-input GEMM:
// C[r][c] = sum_k A[r][k]*B[c][k]).
template <int NSTEP>
__device__ __forceinline__ void gemm_tile_acc(
    const __hip_bfloat16* __restrict__ Abase,
    const __hip_bfloat16* __restrict__ Bbase,
    int lda, int ldb,
    __hip_bfloat16* As, __hip_bfloat16* Bs,
    int lane, int wr, int wc, f32x4 acc[4][4]) {
  for (int s = 0; s < NSTEP; ++s) {
    __syncthreads();                       // previous compute done
    stage_tile(Abase + s * BK, lda, As);
    stage_tile(Bbase + s * BK, ldb, Bs);
    __syncthreads();                       // drains vmcnt
    short8 af[2][4], bf[2][4];
#pragma unroll
    for (int kk = 0; kk < 2; ++kk) {
#pragma unroll
      for (int m = 0; m < 4; ++m)
        af[kk][m] = *(const short8*)(As + (wr * 64 + m * 16 + (lane & 15)) * BK +
                                     kk * 32 + (lane >> 4) * 8);
#pragma unroll
      for (int n = 0; n < 4; ++n)
        bf[kk][n] = *(const short8*)(Bs + (wc * 64 + n * 16 + (lane & 15)) * BK +
                                     kk * 32 + (lane >> 4) * 8);
    }
#pragma unroll
    for (int kk = 0; kk < 2; ++kk)
#pragma unroll
      for (int m = 0; m < 4; ++m)
#pragma unroll
        for (int n = 0; n < 4; ++n)
          acc[m][n] = __builtin_amdgcn_mfma_f32_16x16x32_bf16(
              af[kk][m], bf[kk][n], acc[m][n], 0, 0, 0);
  }
}

// ---------------------------------------------------------------------------
// fp32 -> bf16 bulk convert (8 elems/thread/iter)
__global__ void cvt_bf16_kernel(const float* __restrict__ in,
                                __hip_bfloat16* __restrict__ outp, long n8) {
  long i = (long)blockIdx.x * 256 + threadIdx.x;
  const long stride = (long)gridDim.x * 256;
  for (; i < n8; i += stride) {
    const float4* p = (const float4*)in + i * 2;
    float4 v0 = p[0], v1 = p[1];
    union { __hip_bfloat16 h[8]; short8 v; } u;
    u.h[0] = __float2bfloat16(v0.x); u.h[1] = __float2bfloat16(v0.y);
    u.h[2] = __float2bfloat16(v0.z); u.h[3] = __float2bfloat16(v0.w);
    u.h[4] = __float2bfloat16(v1.x); u.h[5] = __float2bfloat16(v1.y);
    u.h[6] = __float2bfloat16(v1.z); u.h[7] = __float2bfloat16(v1.w);
    ((short8*)outp)[i] = u.v;
  }
}

// ---------------------------------------------------------------------------
// out_bf[row][col] = sum_d A[row][d]*W[col][d] + bias[col]   (torch Linear)
__global__ __launch_bounds__(256, 2)
void proj_kernel(const __hip_bfloat16* __restrict__ A,
                 const __hip_bfloat16* __restrict__ W,
                 const float* __restrict__ bias,
                 __hip_bfloat16* __restrict__ outp) {
  __shared__ __align__(16) __hip_bfloat16 As[TS * BK];
  __shared__ __align__(16) __hip_bfloat16 Bs[TS * BK];
  const int t = threadIdx.x, lane = t & 63, wave = t >> 6;
  const int wr = wave >> 1, wc = wave & 1;
  const int nt = blockIdx.x, mt = blockIdx.y;
  f32x4 acc[4][4];
#pragma unroll
  for (int m = 0; m < 4; ++m)
#pragma unroll
    for (int n = 0; n < 4; ++n) acc[m][n] = (f32x4){0.f, 0.f, 0.f, 0.f};

  gemm_tile_acc<DMODEL / BK>(A + (size_t)mt * TS * DMODEL,
                             W + (size_t)nt * TS * DMODEL,
                             DMODEL, DMODEL, As, Bs, lane, wr, wc, acc);
#pragma unroll
  for (int n = 0; n < 4; ++n) {
    const int col = nt * TS + wc * 64 + n * 16 + (lane & 15);
    const float bcol = bias[col];
#pragma unroll
    for (int m = 0; m < 4; ++m) {
      const int row0 = mt * TS + wr * 64 + m * 16 + ((lane >> 4) * 4);
#pragma unroll
      for (int j = 0; j < 4; ++j)
        outp[(size_t)(row0 + j) * DMODEL + col] =
            __float2bfloat16(acc[m][n][j] + bcol);
    }
  }
}

// ---------------------------------------------------------------------------
// Pass A: rZ[q] = 1 / sum_{k unmasked} exp(s_qk), 0 if empty.
// Block = (q-tile, batch); loops all 16 k-tiles.
__global__ __launch_bounds__(256, 2)
void passA_kernel(const __hip_bfloat16* __restrict__ Qb,
                  const __hip_bfloat16* __restrict__ Kb,
                  const int* __restrict__ mask,
                  float* __restrict__ rZ, int b0) {
  __shared__ __align__(16) __hip_bfloat16 As[TS * BK];
  __shared__ __align__(16) __hip_bfloat16 Bs[TS * BK];
  __shared__ float red[2][TS];
  const int t = threadIdx.x, lane = t & 63, wave = t >> 6;
  const int wr = wave >> 1, wc = wave & 1;
  const int qt = blockIdx.x, cb = blockIdx.y, b = b0 + cb;
  const __hip_bfloat16* Qbase = Qb + ((size_t)cb * SEQ + qt * TS) * DMODEL;
  const __hip_bfloat16* Kall  = Kb + (size_t)cb * SEQ * DMODEL;

  float zp[4][4] = {};  // [m][j] partial row sums
  for (int kt = 0; kt < SEQ / TS; ++kt) {
    f32x4 acc[4][4];
#pragma unroll
    for (int m = 0; m < 4; ++m)
#pragma unroll
      for (int n = 0; n < 4; ++n) acc[m][n] = (f32x4){0.f, 0.f, 0.f, 0.f};
    gemm_tile_acc<DMODEL / BK>(Qbase, Kall + (size_t)kt * TS * DMODEL,
                               DMODEL, DMODEL, As, Bs, lane, wr, wc, acc);
    int mk[4];
#pragma unroll
    for (int n = 0; n < 4; ++n)
      mk[n] = mask[(size_t)b * SEQ + kt * TS + wc * 64 + n * 16 + (lane & 15)];
#pragma unroll
    for (int m = 0; m < 4; ++m)
#pragma unroll
      for (int n = 0; n < 4; ++n)
#pragma unroll
        for (int j = 0; j < 4; ++j) {
          const float e = mk[n] ? __expf(acc[m][n][j] * 0.03125f) : 0.f;
          zp[m][j] += e;
        }
  }
  // reduce over the 16 col-lanes of each group
#pragma unroll
  for (int m = 0; m < 4; ++m)
#pragma unroll
    for (int j = 0; j < 4; ++j) {
      float v = zp[m][j];
      v += __shfl_xor(v, 1); v += __shfl_xor(v, 2);
      v += __shfl_xor(v, 4); v += __shfl_xor(v, 8);
      zp[m][j] = v;
    }
  if ((lane & 15) == 0) {
    const int g = lane >> 4;
#pragma unroll
    for (int m = 0; m < 4; ++m)
#pragma unroll
      for (int j = 0; j < 4; ++j)
        red[wc][wr * 64 + m * 16 + g * 4 + j] = zp[m][j];
  }
  __syncthreads();
  if (t < TS) {
    const float z = red[0][t] + red[1][t];
    rZ[(size_t)cb * SEQ + qt * TS + t] = (z > 0.f) ? (1.f / z) : 0.f;
  }
}

// ---------------------------------------------------------------------------
// Pass B: w[k] = mask[k] ? sum_q exp(s_qk) * rZ[q] : 0; also per-tile sum of w.
// Block = (k-tile, batch); loops all 16 q-tiles. C[k][q] = K·Q^T.
__global__ __launch_bounds__(256, 2)
void passB_kernel(const __hip_bfloat16* __restrict__ Kb,
                  const __hip_bfloat16* __restrict__ Qb,
                  const int* __restrict__ mask,
                  const float* __restrict__ rZ,
                  float* __restrict__ wout, float* __restrict__ sumwp, int b0) {
  __shared__ __align__(16) __hip_bfloat16 As[TS * BK];
  __shared__ __align__(16) __hip_bfloat16 Bs[TS * BK];
  __shared__ float red[2][TS];
  __shared__ float ssum[TS];
  const int t = threadIdx.x, lane = t & 63, wave = t >> 6;
  const int wr = wave >> 1, wc = wave & 1;
  const int kt = blockIdx.x, cb = blockIdx.y, b = b0 + cb;
  const __hip_bfloat16* Kbase = Kb + ((size_t)cb * SEQ + kt * TS) * DMODEL;
  const __hip_bfloat16* Qall  = Qb + (size_t)cb * SEQ * DMODEL;

  float wp[4][4] = {};
  for (int qt = 0; qt < SEQ / TS; ++qt) {
    f32x4 acc[4][4];
#pragma unroll
    for (int m = 0; m < 4; ++m)
#pragma unroll
      for (int n = 0; n < 4; ++n) acc[m][n] = (f32x4){0.f, 0.f, 0.f, 0.f};
    gemm_tile_acc<DMODEL / BK>(Kbase, Qall + (size_t)qt * TS * DMODEL,
                               DMODEL, DMODEL, As, Bs, lane, wr, wc, acc);
    float rz[4];
#pragma unroll
    for (int n = 0; n < 4; ++n)
      rz[n] = rZ[(size_t)cb * SEQ + qt * TS + wc * 64 + n * 16 + (lane & 15)];
#pragma unroll
    for (int m = 0; m < 4; ++m)
#pragma unroll
      for (int n = 0; n < 4; ++n)
#pragma unroll
        for (int j = 0; j < 4; ++j)
          wp[m][j] += __expf(acc[m][n][j] * 0.03125f) * rz[n];
  }
#pragma unroll
  for (int m = 0; m < 4; ++m)
#pragma unroll
    for (int j = 0; j < 4; ++j) {
      float v = wp[m][j];
      v += __shfl_xor(v, 1); v += __shfl_xor(v, 2);
      v += __shfl_xor(v, 4); v += __shfl_xor(v, 8);
      wp[m][j] = v;
    }
  if ((lane & 15) == 0) {
    const int g = lane >> 4;
#pragma unroll
    for (int m = 0; m < 4; ++m)
#pragma unroll
      for (int j = 0; j < 4; ++j)
        red[wc][wr * 64 + m * 16 + g * 4 + j] = wp[m][j];
  }
  __syncthreads();
  if (t < TS) {
    const int k = kt * TS + t;
    float wv = red[0][t] + red[1][t];
    if (!mask[(size_t)b * SEQ + k]) wv = 0.f;
    wout[(size_t)cb * SEQ + k] = wv;
    ssum[t] = wv;
  }
  __syncthreads();
  if (t < 64) {
    float v = ssum[t] + ssum[t + 64];
    v += __shfl_down(v, 32); v += __shfl_down(v, 16); v += __shfl_down(v, 8);
    v += __shfl_down(v, 4);  v += __shfl_down(v, 2);  v += __shfl_down(v, 1);
    if (t == 0) sumwp[b * 16 + kt] = v;
  }
}

// ---------------------------------------------------------------------------
// wxp[kq][b][d] = sum_{k in chunk kq} w[k] * x[b][k][d]   (fp32)
__global__ void wxpart_kernel(const float* __restrict__ x,
                              const float* __restrict__ w,
                              float* __restrict__ wxp, int b0) {
  const int dt = blockIdx.x, cb = blockIdx.y, kq = blockIdx.z;
  const int b = b0 + cb;
  const int d = dt * 256 + threadIdx.x;
  const float* xb = x + ((size_t)b * SEQ + (size_t)kq * (SEQ / KSPLIT)) * DMODEL;
  const float* wb = w + (size_t)cb * SEQ + (size_t)kq * (SEQ / KSPLIT);
  float acc = 0.f;
#pragma unroll 4
  for (int k = 0; k < SEQ / KSPLIT; ++k)
    acc += wb[k] * xb[(size_t)k * DMODEL + d];
  wxp[((size_t)kq * NBATCH + b) * DMODEL + d] = acc;
}

// ---------------------------------------------------------------------------
// out[b][e] = ( sum_d (sum_kq wxp[kq][b][d]) * Wv[e][d] + sumw[b]*bv[e] ) / SEQ
__global__ void final_kernel(const float* __restrict__ wxp,
                             const float* __restrict__ sumwp,
                             const float* __restrict__ Wv,
                             const float* __restrict__ bv,
                             float* __restrict__ out) {
  const int b = blockIdx.y, eg = blockIdx.x;
  const int wave = threadIdx.x >> 6, lane = threadIdx.x & 63;
  const int e = eg * 4 + wave;
  float acc = 0.f;
  for (int d = lane; d < DMODEL; d += 64) {
    float wx = 0.f;
#pragma unroll
    for (int kq = 0; kq < KSPLIT; ++kq)
      wx += wxp[((size_t)kq * NBATCH + b) * DMODEL + d];
    acc += wx * Wv[(size_t)e * DMODEL + d];
  }
  acc += __shfl_down(acc, 32); acc += __shfl_down(acc, 16);
  acc += __shfl_down(acc, 8);  acc += __shfl_down(acc, 4);
  acc += __shfl_down(acc, 2);  acc += __shfl_down(acc, 1);
  if (lane == 0) {
    float sw = 0.f;
#pragma unroll
    for (int i = 0; i < 16; ++i) sw += sumwp[b * 16 + i];
    out[(size_t)b * DMODEL + e] = (acc + sw * bv[e]) * (1.f / (float)SEQ);
  }
}

// ---------------------------------------------------------------------------
extern "C" void kernel_launch(void* const* d_in, const int* in_sizes, int n_in,
                              void* d_out, int out_size, void* d_ws, size_t ws_size,
                              hipStream_t stream) {
  const float* x  = (const float*)d_in[0];
  const int* mask = (const int*)d_in[1];
  const float* Wq = (const float*)d_in[2];
  const float* bq = (const float*)d_in[3];
  const float* Wk = (const float*)d_in[4];
  const float* bk = (const float*)d_in[5];
  const float* Wv = (const float*)d_in[6];
  const float* bv = (const float*)d_in[7];
  float* out = (float*)d_out;

  char* ws = (char*)d_ws;
  size_t off = 0;
  auto alloc = [&](size_t bytes) -> void* {
    void* p = ws + off;
    off += (bytes + 255) & ~(size_t)255;
    return p;
  };
  __hip_bfloat16* Wq_bf = (__hip_bfloat16*)alloc((size_t)DMODEL * DMODEL * 2);
  __hip_bfloat16* Wk_bf = (__hip_bfloat16*)alloc((size_t)DMODEL * DMODEL * 2);
  float* wxp   = (float*)alloc((size_t)KSPLIT * NBATCH * DMODEL * 4);
  float* sumwp = (float*)alloc((size_t)NBATCH * 16 * 4);
  const size_t fixed = off;
  const size_t per_batch =
      (size_t)3 * SEQ * DMODEL * 2 + (size_t)2 * SEQ * 4 + 5 * 256;
  long avail = (long)ws_size - (long)fixed;
  int NB = (int)(avail / (long)per_batch);
  if (NB < 1) NB = 1;
  if (NB > NBATCH) NB = NBATCH;
  __hip_bfloat16* x_bf = (__hip_bfloat16*)alloc((size_t)NB * SEQ * DMODEL * 2);
  __hip_bfloat16* Qb   = (__hip_bfloat16*)alloc((size_t)NB * SEQ * DMODEL * 2);
  __hip_bfloat16* Kb   = (__hip_bfloat16*)alloc((size_t)NB * SEQ * DMODEL * 2);
  float* rZ   = (float*)alloc((size_t)NB * SEQ * 4);
  float* wbuf = (float*)alloc((size_t)NB * SEQ * 4);

  {
    const long n8 = (long)DMODEL * DMODEL / 8;
    cvt_bf16_kernel<<<dim3(512), dim3(256), 0, stream>>>(Wq, Wq_bf, n8);
    cvt_bf16_kernel<<<dim3(512), dim3(256), 0, stream>>>(Wk, Wk_bf, n8);
  }
  for (int b0 = 0; b0 < NBATCH; b0 += NB) {
    const int nb = (NBATCH - b0 < NB) ? (NBATCH - b0) : NB;
    const long n8 = (long)nb * SEQ * DMODEL / 8;
    cvt_bf16_kernel<<<dim3(2048), dim3(256), 0, stream>>>(
        x + (size_t)b0 * SEQ * DMODEL, x_bf, n8);
    proj_kernel<<<dim3(DMODEL / TS, nb * (SEQ / TS)), dim3(256), 0, stream>>>(
        x_bf, Wq_bf, bq, Qb);
    proj_kernel<<<dim3(DMODEL / TS, nb * (SEQ / TS)), dim3(256), 0, stream>>>(
        x_bf, Wk_bf, bk, Kb);
    passA_kernel<<<dim3(SEQ / TS, nb), dim3(256), 0, stream>>>(
        Qb, Kb, mask, rZ, b0);
    passB_kernel<<<dim3(SEQ / TS, nb), dim3(256), 0, stream>>>(
        Kb, Qb, mask, rZ, wbuf, sumwp, b0);
    wxpart_kernel<<<dim3(DMODEL / 256, nb, KSPLIT), dim3(256), 0, stream>>>(
        x, wbuf, wxp, b0);
  }
  final_kernel<<<dim3(DMODEL / 4, NBATCH), dim3(256), 0, stream>>>(
      wxp, sumwp, Wv, bv, out);
}

// Round 2
// 475.840 us; speedup vs baseline: 1.9585x; 1.9585x over previous
//
#include <hip/hip_runtime.h>
#include <hip/hip_bf16.h>
#include <stdint.h>

#define NBATCH 16
#define SEQ    2048
#define DMODEL 1024
#define TS     128     // output tile (M and N)
#define BK     64      // K-step per stage
#define KSPLIT 8       // k-range split for the w^T x GEMV

typedef __attribute__((ext_vector_type(8))) short short8;   // 8 bf16 = 4 VGPRs
typedef __attribute__((ext_vector_type(4))) float f32x4;

__device__ __forceinline__ float bf2f(short s) {
  union { uint32_t u; float f; } c;
  c.u = ((uint32_t)(uint16_t)s) << 16;
  return c.f;
}

// ---------------------------------------------------------------------------
// async global -> LDS, 16B per lane. LDS dest is wave-uniform base + lane*16.
__device__ __forceinline__ void gload16(const void* g, void* l) {
  __builtin_amdgcn_global_load_lds(
      (const __attribute__((address_space(1))) void*)g,
      (__attribute__((address_space(3))) void*)l, 16, 0, 0);
}

// Stage a [TS=128][BK=64] bf16 tile (16 KB) from row-major global (ld elems)
// into linear row-major LDS. 256 threads, 4 issues/thread.
__device__ __forceinline__ void stage_tile(const __hip_bfloat16* __restrict__ g,
                                           int ld, __hip_bfloat16* lds) {
  const int t = threadIdx.x;
  const int wave = t >> 6;
  const char* gb = (const char*)g;
  char* lb = (char*)lds + wave * 1024;   // wave-uniform; HW adds lane*16
#pragma unroll
  for (int it = 0; it < 4; ++it) {
    const int i   = it * 4096 + t * 16;  // linear byte in tile
    const int row = i >> 7;              // 128 B per row
    const int cb  = i & 127;
    gload16(gb + (size_t)row * (ld * 2) + cb, lb + it * 4096);
  }
}

// C[r][c] = sum_k A[r][k]*B[c][k] over NSTEP*BK, 128x128 tile, 4 waves (2x2).
template <int NSTEP>
__device__ __forceinline__ void gemm_tile_acc(
    const __hip_bfloat16* __restrict__ Abase,
    const __hip_bfloat16* __restrict__ Bbase,
    int lda, int ldb,
    __hip_bfloat16* As, __hip_bfloat16* Bs,
    int lane, int wr, int wc, f32x4 acc[4][4]) {
  for (int s = 0; s < NSTEP; ++s) {
    __syncthreads();                       // previous compute done
    stage_tile(Abase + s * BK, lda, As);
    stage_tile(Bbase + s * BK, ldb, Bs);
    __syncthreads();                       // drains vmcnt
    short8 af[2][4], bf[2][4];
#pragma unroll
    for (int kk = 0; kk < 2; ++kk) {
#pragma unroll
      for (int m = 0; m < 4; ++m)
        af[kk][m] = *(const short8*)(As + (wr * 64 + m * 16 + (lane & 15)) * BK +
                                     kk * 32 + (lane >> 4) * 8);
#pragma unroll
      for (int n = 0; n < 4; ++n)
        bf[kk][n] = *(const short8*)(Bs + (wc * 64 + n * 16 + (lane & 15)) * BK +
                                     kk * 32 + (lane >> 4) * 8);
    }
#pragma unroll
    for (int kk = 0; kk < 2; ++kk)
#pragma unroll
      for (int m = 0; m < 4; ++m)
#pragma unroll
        for (int n = 0; n < 4; ++n)
          acc[m][n] = __builtin_amdgcn_mfma_f32_16x16x32_bf16(
              af[kk][m], bf[kk][n], acc[m][n], 0, 0, 0);
  }
}

// ---------------------------------------------------------------------------
// fp32 -> bf16 bulk convert (8 elems/thread/iter)
__global__ void cvt_bf16_kernel(const float* __restrict__ in,
                                __hip_bfloat16* __restrict__ outp, long n8) {
  long i = (long)blockIdx.x * 256 + threadIdx.x;
  const long stride = (long)gridDim.x * 256;
  for (; i < n8; i += stride) {
    const float4* p = (const float4*)in + i * 2;
    float4 v0 = p[0], v1 = p[1];
    union { __hip_bfloat16 h[8]; short8 v; } u;
    u.h[0] = __float2bfloat16(v0.x); u.h[1] = __float2bfloat16(v0.y);
    u.h[2] = __float2bfloat16(v0.z); u.h[3] = __float2bfloat16(v0.w);
    u.h[4] = __float2bfloat16(v1.x); u.h[5] = __float2bfloat16(v1.y);
    u.h[6] = __float2bfloat16(v1.z); u.h[7] = __float2bfloat16(v1.w);
    ((short8*)outp)[i] = u.v;
  }
}

// ---------------------------------------------------------------------------
// out_bf[row][col] = sum_d A[row][d]*W[col][d] + bias[col]   (torch Linear)
__global__ __launch_bounds__(256, 2)
void proj_kernel(const __hip_bfloat16* __restrict__ A,
                 const __hip_bfloat16* __restrict__ W,
                 const float* __restrict__ bias,
                 __hip_bfloat16* __restrict__ outp) {
  __shared__ __align__(16) __hip_bfloat16 As[TS * BK];
  __shared__ __align__(16) __hip_bfloat16 Bs[TS * BK];
  const int t = threadIdx.x, lane = t & 63, wave = t >> 6;
  const int wr = wave >> 1, wc = wave & 1;
  const int nt = blockIdx.x, mt = blockIdx.y;
  f32x4 acc[4][4];
#pragma unroll
  for (int m = 0; m < 4; ++m)
#pragma unroll
    for (int n = 0; n < 4; ++n) acc[m][n] = (f32x4){0.f, 0.f, 0.f, 0.f};

  gemm_tile_acc<DMODEL / BK>(A + (size_t)mt * TS * DMODEL,
                             W + (size_t)nt * TS * DMODEL,
                             DMODEL, DMODEL, As, Bs, lane, wr, wc, acc);
#pragma unroll
  for (int n = 0; n < 4; ++n) {
    const int col = nt * TS + wc * 64 + n * 16 + (lane & 15);
    const float bcol = bias[col];
#pragma unroll
    for (int m = 0; m < 4; ++m) {
      const int row0 = mt * TS + wr * 64 + m * 16 + ((lane >> 4) * 4);
#pragma unroll
      for (int j = 0; j < 4; ++j)
        outp[(size_t)(row0 + j) * DMODEL + col] =
            __float2bfloat16(acc[m][n][j] + bcol);
    }
  }
}

// ---------------------------------------------------------------------------
// passA: one dispatch computes ALL (kt,qt) S-tiles for nb batches.
// E[b][k][q] = mask[b][k] ? exp(s_kq/32) : 0   (bf16, S^T layout)
// Zpart[b][kt][q] = partial sum over this kt tile's 128 k rows.
// blockIdx.x = qt + 16*kt  (qt fastest -> qt%8 pins XCD, K panel L2-resident)
__global__ __launch_bounds__(256, 2)
void passA_kernel(const __hip_bfloat16* __restrict__ Kb,
                  const __hip_bfloat16* __restrict__ Qb,
                  const int* __restrict__ mask,
                  __hip_bfloat16* __restrict__ E,
                  float* __restrict__ Zpart, int b0) {
  __shared__ __align__(16) __hip_bfloat16 As[TS * BK];
  __shared__ __align__(16) __hip_bfloat16 Bs[TS * BK];
  __shared__ float red[2][TS];
  const int t = threadIdx.x, lane = t & 63, wave = t >> 6;
  const int wr = wave >> 1, wc = wave & 1;
  const int qt = blockIdx.x & 15, kt = blockIdx.x >> 4;
  const int cb = blockIdx.y, b = b0 + cb;

  f32x4 acc[4][4];
#pragma unroll
  for (int m = 0; m < 4; ++m)
#pragma unroll
    for (int n = 0; n < 4; ++n) acc[m][n] = (f32x4){0.f, 0.f, 0.f, 0.f};
  gemm_tile_acc<DMODEL / BK>(Kb + ((size_t)cb * SEQ + kt * TS) * DMODEL,
                             Qb + ((size_t)cb * SEQ + qt * TS) * DMODEL,
                             DMODEL, DMODEL, As, Bs, lane, wr, wc, acc);

  float zc[4] = {0.f, 0.f, 0.f, 0.f};  // per-n (q-col) partial Z
#pragma unroll
  for (int m = 0; m < 4; ++m) {
    const int krow0 = wr * 64 + m * 16 + ((lane >> 4) * 4);
    const int4 mk4 = *(const int4*)&mask[(size_t)b * SEQ + kt * TS + krow0];
#pragma unroll
    for (int j = 0; j < 4; ++j) {
      const int km = (j == 0) ? mk4.x : (j == 1) ? mk4.y : (j == 2) ? mk4.z : mk4.w;
      const size_t krow = (size_t)kt * TS + krow0 + j;
      __hip_bfloat16* Erow = E + ((size_t)cb * SEQ + krow) * SEQ + qt * TS;
#pragma unroll
      for (int n = 0; n < 4; ++n) {
        const float e = km ? __expf(acc[m][n][j] * 0.03125f) : 0.f;
        zc[n] += e;
        Erow[wc * 64 + n * 16 + (lane & 15)] = __float2bfloat16(e);
      }
    }
  }
  // reduce over the 4 row-groups (lanes sharing lane&15)
#pragma unroll
  for (int n = 0; n < 4; ++n) {
    float v = zc[n];
    v += __shfl_xor(v, 16);
    v += __shfl_xor(v, 32);
    if (lane < 16) red[wr][wc * 64 + n * 16 + lane] = v;
  }
  __syncthreads();
  if (t < TS)
    Zpart[((size_t)cb * 16 + kt) * SEQ + qt * TS + t] = red[0][t] + red[1][t];
}

// ---------------------------------------------------------------------------
// rZ[b][q] = 1 / sum_kt Zpart[b][kt][q]  (0 if empty)
__global__ void zinv_kernel(const float* __restrict__ Zpart,
                            float* __restrict__ rZ, int n) {
  const int idx = blockIdx.x * 256 + threadIdx.x;
  if (idx >= n) return;
  const int cb = idx >> 11, q = idx & (SEQ - 1);
  float z = 0.f;
#pragma unroll
  for (int kt = 0; kt < 16; ++kt)
    z += Zpart[((size_t)cb * 16 + kt) * SEQ + q];
  rZ[(size_t)cb * SEQ + q] = (z > 0.f) ? (1.f / z) : 0.f;
}

// ---------------------------------------------------------------------------
// passB: w[k] = sum_q E[k][q] * rZ[q]  (streaming; rZ slice held in registers)
// block = 4 waves, each wave owns 4 k-rows; grid (SEQ/16, nb)
__global__ __launch_bounds__(256)
void passB_kernel(const __hip_bfloat16* __restrict__ E,
                  const float* __restrict__ rZ,
                  float* __restrict__ wout) {
  const int t = threadIdx.x, lane = t & 63, wave = t >> 6;
  const int cb = blockIdx.y;
  // each lane's fixed 32 rZ values: q = it*512 + lane*8 + e
  float4 rzv[4][2];
#pragma unroll
  for (int it = 0; it < 4; ++it) {
    const float4* p = (const float4*)(rZ + (size_t)cb * SEQ + it * 512 + lane * 8);
    rzv[it][0] = p[0];
    rzv[it][1] = p[1];
  }
  const int kbase = blockIdx.x * 16 + wave * 4;
#pragma unroll
  for (int r = 0; r < 4; ++r) {
    const int k = kbase + r;
    const short8* Ep = (const short8*)(E + ((size_t)cb * SEQ + k) * SEQ);
    float s = 0.f;
#pragma unroll
    for (int it = 0; it < 4; ++it) {
      const short8 v = Ep[it * 64 + lane];
      const float* rz = (const float*)&rzv[it][0];
#pragma unroll
      for (int e = 0; e < 8; ++e) s += bf2f(v[e]) * rz[e];
    }
    s += __shfl_down(s, 32); s += __shfl_down(s, 16); s += __shfl_down(s, 8);
    s += __shfl_down(s, 4);  s += __shfl_down(s, 2);  s += __shfl_down(s, 1);
    if (lane == 0) wout[(size_t)cb * SEQ + k] = s;
  }
}

// ---------------------------------------------------------------------------
// sumw_all[b] = sum_k w[k]
__global__ void sumw_kernel(const float* __restrict__ w,
                            float* __restrict__ sumw_all, int b0) {
  __shared__ float sred[4];
  const int t = threadIdx.x, lane = t & 63, wave = t >> 6;
  const int cb = blockIdx.x;
  float v = 0.f;
  for (int k = t; k < SEQ; k += 256) v += w[(size_t)cb * SEQ + k];
  v += __shfl_down(v, 32); v += __shfl_down(v, 16); v += __shfl_down(v, 8);
  v += __shfl_down(v, 4);  v += __shfl_down(v, 2);  v += __shfl_down(v, 1);
  if (lane == 0) sred[wave] = v;
  __syncthreads();
  if (t == 0) sumw_all[b0 + cb] = sred[0] + sred[1] + sred[2] + sred[3];
}

// ---------------------------------------------------------------------------
// wxp[kq][b][d] = sum_{k in chunk kq} w[k] * x[b][k][d]   (fp32)
__global__ void wxpart_kernel(const float* __restrict__ x,
                              const float* __restrict__ w,
                              float* __restrict__ wxp, int b0) {
  const int dt = blockIdx.x, cb = blockIdx.y, kq = blockIdx.z;
  const int b = b0 + cb;
  const int d = dt * 256 + threadIdx.x;
  const float* xb = x + ((size_t)b * SEQ + (size_t)kq * (SEQ / KSPLIT)) * DMODEL;
  const float* wb = w + (size_t)cb * SEQ + (size_t)kq * (SEQ / KSPLIT);
  float acc = 0.f;
#pragma unroll 4
  for (int k = 0; k < SEQ / KSPLIT; ++k)
    acc += wb[k] * xb[(size_t)k * DMODEL + d];
  wxp[((size_t)kq * NBATCH + b) * DMODEL + d] = acc;
}

// ---------------------------------------------------------------------------
// out[b][e] = ( sum_d (sum_kq wxp[kq][b][d]) * Wv[e][d] + sumw[b]*bv[e] ) / SEQ
__global__ void final_kernel(const float* __restrict__ wxp,
                             const float* __restrict__ sumw_all,
                             const float* __restrict__ Wv,
                             const float* __restrict__ bv,
                             float* __restrict__ out) {
  const int b = blockIdx.y, eg = blockIdx.x;
  const int wave = threadIdx.x >> 6, lane = threadIdx.x & 63;
  const int e = eg * 4 + wave;
  float acc = 0.f;
  for (int d = lane; d < DMODEL; d += 64) {
    float wx = 0.f;
#pragma unroll
    for (int kq = 0; kq < KSPLIT; ++kq)
      wx += wxp[((size_t)kq * NBATCH + b) * DMODEL + d];
    acc += wx * Wv[(size_t)e * DMODEL + d];
  }
  acc += __shfl_down(acc, 32); acc += __shfl_down(acc, 16);
  acc += __shfl_down(acc, 8);  acc += __shfl_down(acc, 4);
  acc += __shfl_down(acc, 2);  acc += __shfl_down(acc, 1);
  if (lane == 0)
    out[(size_t)b * DMODEL + e] =
        (acc + sumw_all[b] * bv[e]) * (1.f / (float)SEQ);
}

// ---------------------------------------------------------------------------
extern "C" void kernel_launch(void* const* d_in, const int* in_sizes, int n_in,
                              void* d_out, int out_size, void* d_ws, size_t ws_size,
                              hipStream_t stream) {
  const float* x  = (const float*)d_in[0];
  const int* mask = (const int*)d_in[1];
  const float* Wq = (const float*)d_in[2];
  const float* bq = (const float*)d_in[3];
  const float* Wk = (const float*)d_in[4];
  const float* bk = (const float*)d_in[5];
  const float* Wv = (const float*)d_in[6];
  const float* bv = (const float*)d_in[7];
  float* out = (float*)d_out;

  char* ws = (char*)d_ws;
  size_t off = 0;
  auto alloc = [&](size_t bytes) -> void* {
    void* p = ws + off;
    off += (bytes + 255) & ~(size_t)255;
    return p;
  };
  __hip_bfloat16* Wq_bf = (__hip_bfloat16*)alloc((size_t)DMODEL * DMODEL * 2);
  __hip_bfloat16* Wk_bf = (__hip_bfloat16*)alloc((size_t)DMODEL * DMODEL * 2);
  float* wxp      = (float*)alloc((size_t)KSPLIT * NBATCH * DMODEL * 4);
  float* sumw_all = (float*)alloc((size_t)NBATCH * 4);
  const size_t fixed = off;
  // per-batch: union(x_bf 4MB, E 8MB) = 8MB + Qb 4MB + Kb 4MB + Zpart + rZ + w
  const size_t per_batch = (size_t)SEQ * SEQ * 2            // E / x_bf union
                         + (size_t)2 * SEQ * DMODEL * 2     // Qb, Kb
                         + (size_t)16 * SEQ * 4             // Zpart
                         + (size_t)2 * SEQ * 4 + 6 * 256;   // rZ, wbuf, pads
  long avail = (long)ws_size - (long)fixed;
  int NB = (int)(avail / (long)per_batch);
  if (NB < 1) NB = 1;
  if (NB > NBATCH) NB = NBATCH;
  char* xE = (char*)alloc((size_t)NB * SEQ * SEQ * 2);  // x_bf then E (aliased)
  __hip_bfloat16* x_bf = (__hip_bfloat16*)xE;
  __hip_bfloat16* Ebuf = (__hip_bfloat16*)xE;
  __hip_bfloat16* Qb = (__hip_bfloat16*)alloc((size_t)NB * SEQ * DMODEL * 2);
  __hip_bfloat16* Kb = (__hip_bfloat16*)alloc((size_t)NB * SEQ * DMODEL * 2);
  float* Zpart = (float*)alloc((size_t)NB * 16 * SEQ * 4);
  float* rZ    = (float*)alloc((size_t)NB * SEQ * 4);
  float* wbuf  = (float*)alloc((size_t)NB * SEQ * 4);

  {
    const long n8 = (long)DMODEL * DMODEL / 8;
    cvt_bf16_kernel<<<dim3(512), dim3(256), 0, stream>>>(Wq, Wq_bf, n8);
    cvt_bf16_kernel<<<dim3(512), dim3(256), 0, stream>>>(Wk, Wk_bf, n8);
  }
  for (int b0 = 0; b0 < NBATCH; b0 += NB) {
    const int nb = (NBATCH - b0 < NB) ? (NBATCH - b0) : NB;
    const long n8 = (long)nb * SEQ * DMODEL / 8;
    cvt_bf16_kernel<<<dim3(2048), dim3(256), 0, stream>>>(
        x + (size_t)b0 * SEQ * DMODEL, x_bf, n8);
    proj_kernel<<<dim3(DMODEL / TS, nb * (SEQ / TS)), dim3(256), 0, stream>>>(
        x_bf, Wq_bf, bq, Qb);
    proj_kernel<<<dim3(DMODEL / TS, nb * (SEQ / TS)), dim3(256), 0, stream>>>(
        x_bf, Wk_bf, bk, Kb);
    // x_bf dead from here; E aliases it
    passA_kernel<<<dim3(256, nb), dim3(256), 0, stream>>>(
        Kb, Qb, mask, Ebuf, Zpart, b0);
    zinv_kernel<<<dim3((nb * SEQ + 255) / 256), dim3(256), 0, stream>>>(
        Zpart, rZ, nb * SEQ);
    passB_kernel<<<dim3(SEQ / 16, nb), dim3(256), 0, stream>>>(Ebuf, rZ, wbuf);
    sumw_kernel<<<dim3(nb), dim3(256), 0, stream>>>(wbuf, sumw_all, b0);
    wxpart_kernel<<<dim3(DMODEL / 256, nb, KSPLIT), dim3(256), 0, stream>>>(
        x, wbuf, wxp, b0);
  }
  final_kernel<<<dim3(DMODEL / 4, NBATCH), dim3(256), 0, stream>>>(
      wxp, sumw_all, Wv, bv, out);
}

// Round 3
// 415.210 us; speedup vs baseline: 2.2445x; 1.1460x over previous
//
#include <hip/hip_runtime.h>
#include <hip/hip_bf16.h>
#include <stdint.h>

#define NBATCH 16
#define SEQ    2048
#define DMODEL 1024
#define TS     128     // output tile (M and N)
#define BK     64      // K-step per stage
#define KSPLIT 8       // k-range split for the w^T x GEMV

typedef __attribute__((ext_vector_type(8))) short short8;   // 8 bf16 = 4 VGPRs
typedef __attribute__((ext_vector_type(4))) float f32x4;

__device__ __forceinline__ float bf2f(short s) {
  union { uint32_t u; float f; } c;
  c.u = ((uint32_t)(uint16_t)s) << 16;
  return c.f;
}

// ---------------------------------------------------------------------------
// async global -> LDS, 16B per lane. LDS dest is wave-uniform base + lane*16.
__device__ __forceinline__ void gload16(const void* g, void* l) {
  __builtin_amdgcn_global_load_lds(
      (const __attribute__((address_space(1))) void*)g,
      (__attribute__((address_space(3))) void*)l, 16, 0, 0);
}

// Stage a [TS=128][BK=64] bf16 tile (16 KB) from row-major global (ld elems)
// into linear row-major LDS. 256 threads, 4 issues/thread.
__device__ __forceinline__ void stage_tile(const __hip_bfloat16* __restrict__ g,
                                           int ld, __hip_bfloat16* lds) {
  const int t = threadIdx.x;
  const int wave = t >> 6;
  const char* gb = (const char*)g;
  char* lb = (char*)lds + wave * 1024;   // wave-uniform; HW adds lane*16
#pragma unroll
  for (int it = 0; it < 4; ++it) {
    const int i   = it * 4096 + t * 16;  // linear byte in tile
    const int row = i >> 7;              // 128 B per row
    const int cb  = i & 127;
    gload16(gb + (size_t)row * (ld * 2) + cb, lb + it * 4096);
  }
}

// C[r][c] = sum_k A[r][k]*B[c][k] over NSTEP*BK, 128x128 tile, 4 waves (2x2).
template <int NSTEP>
__device__ __forceinline__ void gemm_tile_acc(
    const __hip_bfloat16* __restrict__ Abase,
    const __hip_bfloat16* __restrict__ Bbase,
    int lda, int ldb,
    __hip_bfloat16* As, __hip_bfloat16* Bs,
    int lane, int wr, int wc, f32x4 acc[4][4]) {
  for (int s = 0; s < NSTEP; ++s) {
    __syncthreads();                       // previous compute done
    stage_tile(Abase + s * BK, lda, As);
    stage_tile(Bbase + s * BK, ldb, Bs);
    __syncthreads();                       // drains vmcnt
    short8 af[2][4], bf[2][4];
#pragma unroll
    for (int kk = 0; kk < 2; ++kk) {
#pragma unroll
      for (int m = 0; m < 4; ++m)
        af[kk][m] = *(const short8*)(As + (wr * 64 + m * 16 + (lane & 15)) * BK +
                                     kk * 32 + (lane >> 4) * 8);
#pragma unroll
      for (int n = 0; n < 4; ++n)
        bf[kk][n] = *(const short8*)(Bs + (wc * 64 + n * 16 + (lane & 15)) * BK +
                                     kk * 32 + (lane >> 4) * 8);
    }
#pragma unroll
    for (int kk = 0; kk < 2; ++kk)
#pragma unroll
      for (int m = 0; m < 4; ++m)
#pragma unroll
        for (int n = 0; n < 4; ++n)
          acc[m][n] = __builtin_amdgcn_mfma_f32_16x16x32_bf16(
              af[kk][m], bf[kk][n], acc[m][n], 0, 0, 0);
  }
}

// ---------------------------------------------------------------------------
// fp32 -> bf16 bulk convert (8 elems/thread/iter)
__global__ void cvt_bf16_kernel(const float* __restrict__ in,
                                __hip_bfloat16* __restrict__ outp, long n8) {
  long i = (long)blockIdx.x * 256 + threadIdx.x;
  const long stride = (long)gridDim.x * 256;
  for (; i < n8; i += stride) {
    const float4* p = (const float4*)in + i * 2;
    float4 v0 = p[0], v1 = p[1];
    union { __hip_bfloat16 h[8]; short8 v; } u;
    u.h[0] = __float2bfloat16(v0.x); u.h[1] = __float2bfloat16(v0.y);
    u.h[2] = __float2bfloat16(v0.z); u.h[3] = __float2bfloat16(v0.w);
    u.h[4] = __float2bfloat16(v1.x); u.h[5] = __float2bfloat16(v1.y);
    u.h[6] = __float2bfloat16(v1.z); u.h[7] = __float2bfloat16(v1.w);
    ((short8*)outp)[i] = u.v;
  }
}

// ---------------------------------------------------------------------------
// fp32 [DMODEL][DMODEL] -> bf16 transposed
__global__ void transpose_cvt_kernel(const float* __restrict__ in,
                                     __hip_bfloat16* __restrict__ outp) {
  __shared__ float tile[32][33];
  const int bx = blockIdx.x, by = blockIdx.y;
  const int tx = threadIdx.x & 31, ty = threadIdx.x >> 5;  // 32 x 8
#pragma unroll
  for (int r = 0; r < 32; r += 8)
    tile[ty + r][tx] = in[(size_t)(by * 32 + ty + r) * DMODEL + bx * 32 + tx];
  __syncthreads();
#pragma unroll
  for (int r = 0; r < 32; r += 8)
    outp[(size_t)(bx * 32 + ty + r) * DMODEL + by * 32 + tx] =
        __float2bfloat16(tile[tx][ty + r]);
}

// ---------------------------------------------------------------------------
// t1[d] = sum_e Wq[e][d]*bk[e] (via WqT), t2[d] = sum_e Wk[e][d]*bq[e],
// c = bq.bk.  Grid: 257 blocks; bid<256 -> 4 rows each; bid==256 -> c.
__global__ __launch_bounds__(256)
void prep_vec_kernel(const __hip_bfloat16* __restrict__ WqT,
                     const __hip_bfloat16* __restrict__ WkT,
                     const float* __restrict__ bq, const float* __restrict__ bk,
                     float* __restrict__ t1, float* __restrict__ t2,
                     float* __restrict__ cscal) {
  const int wave = threadIdx.x >> 6, lane = threadIdx.x & 63;
  if (blockIdx.x == 256) {
    if (wave != 0) return;
    float v = 0.f;
#pragma unroll
    for (int it = 0; it < 16; ++it) {
      const int i = it * 64 + lane;
      v += bq[i] * bk[i];
    }
    v += __shfl_down(v, 32); v += __shfl_down(v, 16); v += __shfl_down(v, 8);
    v += __shfl_down(v, 4);  v += __shfl_down(v, 2);  v += __shfl_down(v, 1);
    if (lane == 0) *cscal = v;
    return;
  }
  const int d = blockIdx.x * 4 + wave;
  const short8* qr = (const short8*)(WqT + (size_t)d * DMODEL);
  const short8* kr = (const short8*)(WkT + (size_t)d * DMODEL);
  float a1 = 0.f, a2 = 0.f;
#pragma unroll
  for (int h = 0; h < 2; ++h) {
    const short8 qv = qr[lane * 2 + h];
    const short8 kv = kr[lane * 2 + h];
    const int e0 = lane * 16 + h * 8;
#pragma unroll
    for (int i = 0; i < 8; ++i) {
      a1 += bf2f(qv[i]) * bk[e0 + i];
      a2 += bf2f(kv[i]) * bq[e0 + i];
    }
  }
  a1 += __shfl_down(a1, 32); a1 += __shfl_down(a1, 16); a1 += __shfl_down(a1, 8);
  a1 += __shfl_down(a1, 4);  a1 += __shfl_down(a1, 2);  a1 += __shfl_down(a1, 1);
  a2 += __shfl_down(a2, 32); a2 += __shfl_down(a2, 16); a2 += __shfl_down(a2, 8);
  a2 += __shfl_down(a2, 4);  a2 += __shfl_down(a2, 2);  a2 += __shfl_down(a2, 1);
  if (lane == 0) { t1[d] = a1; t2[d] = a2; }
}

// ---------------------------------------------------------------------------
// u[row] = x_bf[row].t1 + c ; v[row] = x_bf[row].t2    (row = cb*SEQ+q)
__global__ __launch_bounds__(256)
void uv_kernel(const __hip_bfloat16* __restrict__ x_bf,
               const float* __restrict__ t1, const float* __restrict__ t2,
               const float* __restrict__ cscal,
               float* __restrict__ ub, float* __restrict__ vb) {
  const int wave = threadIdx.x >> 6, lane = threadIdx.x & 63;
  const long row = (long)blockIdx.x * 4 + wave;
  const short8* xp = (const short8*)(x_bf + (size_t)row * DMODEL);
  float a1 = 0.f, a2 = 0.f;
#pragma unroll
  for (int h = 0; h < 2; ++h) {
    const short8 xv = xp[lane * 2 + h];
    const int d0 = lane * 16 + h * 8;
#pragma unroll
    for (int i = 0; i < 8; ++i) {
      const float xf = bf2f(xv[i]);
      a1 += xf * t1[d0 + i];
      a2 += xf * t2[d0 + i];
    }
  }
  a1 += __shfl_down(a1, 32); a1 += __shfl_down(a1, 16); a1 += __shfl_down(a1, 8);
  a1 += __shfl_down(a1, 4);  a1 += __shfl_down(a1, 2);  a1 += __shfl_down(a1, 1);
  a2 += __shfl_down(a2, 32); a2 += __shfl_down(a2, 16); a2 += __shfl_down(a2, 8);
  a2 += __shfl_down(a2, 4);  a2 += __shfl_down(a2, 2);  a2 += __shfl_down(a2, 1);
  if (lane == 0) { ub[row] = a1 + *cscal; vb[row] = a2; }
}

// ---------------------------------------------------------------------------
// out_bf[row][col] = sum_d A[row][d]*W[col][d] (+ bias[col] if bias)
__global__ __launch_bounds__(256, 2)
void proj_kernel(const __hip_bfloat16* __restrict__ A,
                 const __hip_bfloat16* __restrict__ W,
                 const float* __restrict__ bias,
                 __hip_bfloat16* __restrict__ outp) {
  __shared__ __align__(16) __hip_bfloat16 As[TS * BK];
  __shared__ __align__(16) __hip_bfloat16 Bs[TS * BK];
  const int t = threadIdx.x, lane = t & 63, wave = t >> 6;
  const int wr = wave >> 1, wc = wave & 1;
  const int nt = blockIdx.x, mt = blockIdx.y;
  f32x4 acc[4][4];
#pragma unroll
  for (int m = 0; m < 4; ++m)
#pragma unroll
    for (int n = 0; n < 4; ++n) acc[m][n] = (f32x4){0.f, 0.f, 0.f, 0.f};

  gemm_tile_acc<DMODEL / BK>(A + (size_t)mt * TS * DMODEL,
                             W + (size_t)nt * TS * DMODEL,
                             DMODEL, DMODEL, As, Bs, lane, wr, wc, acc);
#pragma unroll
  for (int n = 0; n < 4; ++n) {
    const int col = nt * TS + wc * 64 + n * 16 + (lane & 15);
    const float bcol = bias ? bias[col] : 0.f;
#pragma unroll
    for (int m = 0; m < 4; ++m) {
      const int row0 = mt * TS + wr * 64 + m * 16 + ((lane >> 4) * 4);
#pragma unroll
      for (int j = 0; j < 4; ++j)
        outp[(size_t)(row0 + j) * DMODEL + col] =
            __float2bfloat16(acc[m][n][j] + bcol);
    }
  }
}

// ---------------------------------------------------------------------------
// passA: S^T tiles. S^T[k][q] = sum_d' x[k][d']*Y[q][d'] (+u[q]+v[k], then exp)
// E[b][k][q] = mask[b][k] ? exp(s/32) : 0   (bf16, S^T layout)
// Zpart[b][kt][q] = partial Z over this kt tile's 128 k rows.
__global__ __launch_bounds__(256, 2)
void passA_kernel(const __hip_bfloat16* __restrict__ Xb,
                  const __hip_bfloat16* __restrict__ Yb,
                  const int* __restrict__ mask,
                  const float* __restrict__ ub, const float* __restrict__ vb,
                  __hip_bfloat16* __restrict__ E,
                  float* __restrict__ Zpart, int b0) {
  __shared__ __align__(16) __hip_bfloat16 As[TS * BK];
  __shared__ __align__(16) __hip_bfloat16 Bs[TS * BK];
  __shared__ float red[2][TS];
  const int t = threadIdx.x, lane = t & 63, wave = t >> 6;
  const int wr = wave >> 1, wc = wave & 1;
  const int qt = blockIdx.x & 15, kt = blockIdx.x >> 4;
  const int cb = blockIdx.y, b = b0 + cb;

  f32x4 acc[4][4];
#pragma unroll
  for (int m = 0; m < 4; ++m)
#pragma unroll
    for (int n = 0; n < 4; ++n) acc[m][n] = (f32x4){0.f, 0.f, 0.f, 0.f};
  gemm_tile_acc<DMODEL / BK>(Xb + ((size_t)cb * SEQ + kt * TS) * DMODEL,
                             Yb + ((size_t)cb * SEQ + qt * TS) * DMODEL,
                             DMODEL, DMODEL, As, Bs, lane, wr, wc, acc);

  float uq[4];
#pragma unroll
  for (int n = 0; n < 4; ++n)
    uq[n] = ub[(size_t)cb * SEQ + qt * TS + wc * 64 + n * 16 + (lane & 15)];

  float zc[4] = {0.f, 0.f, 0.f, 0.f};  // per-n (q-col) partial Z
#pragma unroll
  for (int m = 0; m < 4; ++m) {
    const int krow0 = wr * 64 + m * 16 + ((lane >> 4) * 4);
    const int4 mk4 = *(const int4*)&mask[(size_t)b * SEQ + kt * TS + krow0];
    const float4 v4 = *(const float4*)&vb[(size_t)cb * SEQ + kt * TS + krow0];
#pragma unroll
    for (int j = 0; j < 4; ++j) {
      const int km = (j == 0) ? mk4.x : (j == 1) ? mk4.y : (j == 2) ? mk4.z : mk4.w;
      const float vj = (j == 0) ? v4.x : (j == 1) ? v4.y : (j == 2) ? v4.z : v4.w;
      const size_t krow = (size_t)kt * TS + krow0 + j;
      __hip_bfloat16* Erow = E + ((size_t)cb * SEQ + krow) * SEQ + qt * TS;
#pragma unroll
      for (int n = 0; n < 4; ++n) {
        const float e =
            km ? __expf((acc[m][n][j] + uq[n] + vj) * 0.03125f) : 0.f;
        zc[n] += e;
        Erow[wc * 64 + n * 16 + (lane & 15)] = __float2bfloat16(e);
      }
    }
  }
#pragma unroll
  for (int n = 0; n < 4; ++n) {
    float v = zc[n];
    v += __shfl_xor(v, 16);
    v += __shfl_xor(v, 32);
    if (lane < 16) red[wr][wc * 64 + n * 16 + lane] = v;
  }
  __syncthreads();
  if (t < TS)
    Zpart[((size_t)cb * 16 + kt) * SEQ + qt * TS + t] = red[0][t] + red[1][t];
}

// ---------------------------------------------------------------------------
// rZ[b][q] = 1 / sum_kt Zpart[b][kt][q]  (0 if empty)
__global__ void zinv_kernel(const float* __restrict__ Zpart,
                            float* __restrict__ rZ, int n) {
  const int idx = blockIdx.x * 256 + threadIdx.x;
  if (idx >= n) return;
  const int cb = idx >> 11, q = idx & (SEQ - 1);
  float z = 0.f;
#pragma unroll
  for (int kt = 0; kt < 16; ++kt)
    z += Zpart[((size_t)cb * 16 + kt) * SEQ + q];
  rZ[(size_t)cb * SEQ + q] = (z > 0.f) ? (1.f / z) : 0.f;
}

// ---------------------------------------------------------------------------
// passB: w[k] = sum_q E[k][q] * rZ[q]
__global__ __launch_bounds__(256)
void passB_kernel(const __hip_bfloat16* __restrict__ E,
                  const float* __restrict__ rZ,
                  float* __restrict__ wout) {
  const int t = threadIdx.x, lane = t & 63, wave = t >> 6;
  const int cb = blockIdx.y;
  float4 rzv[4][2];
#pragma unroll
  for (int it = 0; it < 4; ++it) {
    const float4* p = (const float4*)(rZ + (size_t)cb * SEQ + it * 512 + lane * 8);
    rzv[it][0] = p[0];
    rzv[it][1] = p[1];
  }
  const int kbase = blockIdx.x * 16 + wave * 4;
#pragma unroll
  for (int r = 0; r < 4; ++r) {
    const int k = kbase + r;
    const short8* Ep = (const short8*)(E + ((size_t)cb * SEQ + k) * SEQ);
    float s = 0.f;
#pragma unroll
    for (int it = 0; it < 4; ++it) {
      const short8 v = Ep[it * 64 + lane];
      const float* rz = (const float*)&rzv[it][0];
#pragma unroll
      for (int e = 0; e < 8; ++e) s += bf2f(v[e]) * rz[e];
    }
    s += __shfl_down(s, 32); s += __shfl_down(s, 16); s += __shfl_down(s, 8);
    s += __shfl_down(s, 4);  s += __shfl_down(s, 2);  s += __shfl_down(s, 1);
    if (lane == 0) wout[(size_t)cb * SEQ + k] = s;
  }
}

// ---------------------------------------------------------------------------
// sumw_all[b] = sum_k w[k]
__global__ void sumw_kernel(const float* __restrict__ w,
                            float* __restrict__ sumw_all, int b0) {
  __shared__ float sred[4];
  const int t = threadIdx.x, lane = t & 63, wave = t >> 6;
  const int cb = blockIdx.x;
  float v = 0.f;
  for (int k = t; k < SEQ; k += 256) v += w[(size_t)cb * SEQ + k];
  v += __shfl_down(v, 32); v += __shfl_down(v, 16); v += __shfl_down(v, 8);
  v += __shfl_down(v, 4);  v += __shfl_down(v, 2);  v += __shfl_down(v, 1);
  if (lane == 0) sred[wave] = v;
  __syncthreads();
  if (t == 0) sumw_all[b0 + cb] = sred[0] + sred[1] + sred[2] + sred[3];
}

// ---------------------------------------------------------------------------
// wxp[kq][b][d] = sum_{k in chunk kq} w[k] * x_bf[b][k][d]   (fp32 acc)
__global__ void wxpart_kernel(const __hip_bfloat16* __restrict__ x_bf,
                              const float* __restrict__ w,
                              float* __restrict__ wxp, int b0) {
  const int dt = blockIdx.x, cb = blockIdx.y, kq = blockIdx.z;
  const int b = b0 + cb;
  const int dp = dt * 256 + threadIdx.x;   // bf16 pair index, d = 2*dp
  const __hip_bfloat16* xb =
      x_bf + ((size_t)cb * SEQ + (size_t)kq * (SEQ / KSPLIT)) * DMODEL;
  const float* wb = w + (size_t)cb * SEQ + (size_t)kq * (SEQ / KSPLIT);
  float a0 = 0.f, a1 = 0.f;
#pragma unroll 4
  for (int k = 0; k < SEQ / KSPLIT; ++k) {
    const float wk = wb[k];
    const uint32_t pv = *(const uint32_t*)(xb + (size_t)k * DMODEL + dp * 2);
    a0 += wk * bf2f((short)(pv & 0xffff));
    a1 += wk * bf2f((short)(pv >> 16));
  }
  float2* o = (float2*)&wxp[((size_t)kq * NBATCH + b) * DMODEL + dp * 2];
  *o = make_float2(a0, a1);
}

// ---------------------------------------------------------------------------
// out[b][e] = ( sum_d (sum_kq wxp[kq][b][d]) * Wv[e][d] + sumw[b]*bv[e] ) / SEQ
__global__ void final_kernel(const float* __restrict__ wxp,
                             const float* __restrict__ sumw_all,
                             const float* __restrict__ Wv,
                             const float* __restrict__ bv,
                             float* __restrict__ out) {
  const int b = blockIdx.y, eg = blockIdx.x;
  const int wave = threadIdx.x >> 6, lane = threadIdx.x & 63;
  const int e = eg * 4 + wave;
  float acc = 0.f;
  for (int d = lane; d < DMODEL; d += 64) {
    float wx = 0.f;
#pragma unroll
    for (int kq = 0; kq < KSPLIT; ++kq)
      wx += wxp[((size_t)kq * NBATCH + b) * DMODEL + d];
    acc += wx * Wv[(size_t)e * DMODEL + d];
  }
  acc += __shfl_down(acc, 32); acc += __shfl_down(acc, 16);
  acc += __shfl_down(acc, 8);  acc += __shfl_down(acc, 4);
  acc += __shfl_down(acc, 2);  acc += __shfl_down(acc, 1);
  if (lane == 0)
    out[(size_t)b * DMODEL + e] =
        (acc + sumw_all[b] * bv[e]) * (1.f / (float)SEQ);
}

// ---------------------------------------------------------------------------
extern "C" void kernel_launch(void* const* d_in, const int* in_sizes, int n_in,
                              void* d_out, int out_size, void* d_ws, size_t ws_size,
                              hipStream_t stream) {
  const float* x  = (const float*)d_in[0];
  const int* mask = (const int*)d_in[1];
  const float* Wq = (const float*)d_in[2];
  const float* bq = (const float*)d_in[3];
  const float* Wk = (const float*)d_in[4];
  const float* bk = (const float*)d_in[5];
  const float* Wv = (const float*)d_in[6];
  const float* bv = (const float*)d_in[7];
  float* out = (float*)d_out;

  char* ws = (char*)d_ws;
  size_t off = 0;
  auto alloc = [&](size_t bytes) -> void* {
    void* p = ws + off;
    off += (bytes + 255) & ~(size_t)255;
    return p;
  };
  // ---- persistent (fixed) region ----
  __hip_bfloat16* Mt_bf = (__hip_bfloat16*)alloc((size_t)DMODEL * DMODEL * 2);
  float* wxp      = (float*)alloc((size_t)KSPLIT * NBATCH * DMODEL * 4);
  float* sumw_all = (float*)alloc((size_t)NBATCH * 4);
  float* t1       = (float*)alloc((size_t)DMODEL * 4);
  float* t2       = (float*)alloc((size_t)DMODEL * 4);
  float* cscal    = (float*)alloc(256);
  const size_t fixed = off;

  // ---- transient W^T buffers, aliased over the per-chunk region ----
  // (read only by Mt-GEMM & prep_vec, both of which run before the first
  //  chunk's cvt overwrites this memory; single stream => safe)
  __hip_bfloat16* WqT_bf = (__hip_bfloat16*)(ws + fixed);
  __hip_bfloat16* WkT_bf = (__hip_bfloat16*)(ws + fixed + (size_t)DMODEL * DMODEL * 2);

  // ---- per-chunk region ----
  const size_t per_batch = (size_t)SEQ * DMODEL * 2      // x_bf
                         + (size_t)SEQ * DMODEL * 2      // Y
                         + (size_t)SEQ * SEQ * 2         // E
                         + (size_t)16 * SEQ * 4          // Zpart
                         + (size_t)4 * SEQ * 4           // rZ, w, u, v
                         + 8 * 256;                      // pads
  long avail = (long)ws_size - (long)fixed;
  int NB = (int)(avail / (long)per_batch);
  if (NB < 1) NB = 1;
  if (NB > NBATCH) NB = NBATCH;
  __hip_bfloat16* x_bf = (__hip_bfloat16*)alloc((size_t)NB * SEQ * DMODEL * 2);
  __hip_bfloat16* Yb   = (__hip_bfloat16*)alloc((size_t)NB * SEQ * DMODEL * 2);
  __hip_bfloat16* Ebuf = (__hip_bfloat16*)alloc((size_t)NB * SEQ * SEQ * 2);
  float* Zpart = (float*)alloc((size_t)NB * 16 * SEQ * 4);
  float* rZ    = (float*)alloc((size_t)NB * SEQ * 4);
  float* wbuf  = (float*)alloc((size_t)NB * SEQ * 4);
  float* ub    = (float*)alloc((size_t)NB * SEQ * 4);
  float* vb    = (float*)alloc((size_t)NB * SEQ * 4);

  // ---- one-off prep: W transposes, Mt = (Wq^T Wk) in B^T layout, t1/t2/c ----
  transpose_cvt_kernel<<<dim3(32, 32), dim3(256), 0, stream>>>(Wq, WqT_bf);
  transpose_cvt_kernel<<<dim3(32, 32), dim3(256), 0, stream>>>(Wk, WkT_bf);
  // Mt[d'][d] = sum_e WkT[d'][e]*WqT[d][e] = P[d][d'],  P = Wq^T Wk
  proj_kernel<<<dim3(DMODEL / TS, DMODEL / TS), dim3(256), 0, stream>>>(
      WkT_bf, WqT_bf, nullptr, Mt_bf);
  prep_vec_kernel<<<dim3(257), dim3(256), 0, stream>>>(
      WqT_bf, WkT_bf, bq, bk, t1, t2, cscal);

  for (int b0 = 0; b0 < NBATCH; b0 += NB) {
    const int nb = (NBATCH - b0 < NB) ? (NBATCH - b0) : NB;
    const long n8 = (long)nb * SEQ * DMODEL / 8;
    cvt_bf16_kernel<<<dim3(2048), dim3(256), 0, stream>>>(
        x + (size_t)b0 * SEQ * DMODEL, x_bf, n8);
    // Y[q][d'] = sum_d x[q][d] * Mt[d'][d]
    proj_kernel<<<dim3(DMODEL / TS, nb * (SEQ / TS)), dim3(256), 0, stream>>>(
        x_bf, Mt_bf, nullptr, Yb);
    uv_kernel<<<dim3(nb * SEQ / 4), dim3(256), 0, stream>>>(
        x_bf, t1, t2, cscal, ub, vb);
    passA_kernel<<<dim3(256, nb), dim3(256), 0, stream>>>(
        x_bf, Yb, mask, ub, vb, Ebuf, Zpart, b0);
    zinv_kernel<<<dim3((nb * SEQ + 255) / 256), dim3(256), 0, stream>>>(
        Zpart, rZ, nb * SEQ);
    passB_kernel<<<dim3(SEQ / 16, nb), dim3(256), 0, stream>>>(Ebuf, rZ, wbuf);
    sumw_kernel<<<dim3(nb), dim3(256), 0, stream>>>(wbuf, sumw_all, b0);
    wxpart_kernel<<<dim3(DMODEL / 512, nb, KSPLIT), dim3(256), 0, stream>>>(
        x_bf, wbuf, wxp, b0);
  }
  final_kernel<<<dim3(DMODEL / 4, NBATCH), dim3(256), 0, stream>>>(
      wxp, sumw_all, Wv, bv, out);
}

// Round 4
// 386.701 us; speedup vs baseline: 2.4100x; 1.0737x over previous
//
#include <hip/hip_runtime.h>
#include <hip/hip_bf16.h>
#include <stdint.h>

#define NBATCH 16
#define SEQ    2048
#define DMODEL 1024
#define KSPLIT 8

typedef __attribute__((ext_vector_type(8))) short short8;   // 8 bf16 = 4 VGPRs
typedef __attribute__((ext_vector_type(4))) float f32x4;

__device__ __forceinline__ float bf2f(short s) {
  union { uint32_t u; float f; } c;
  c.u = ((uint32_t)(uint16_t)s) << 16;
  return c.f;
}

// async global -> LDS, 16B/lane. LDS dest = wave-uniform base + lane*16.
__device__ __forceinline__ void gload16(const void* g, void* l) {
  __builtin_amdgcn_global_load_lds(
      (const __attribute__((address_space(1))) void*)g,
      (__attribute__((address_space(3))) void*)l, 16, 0, 0);
}

#define BAR() __builtin_amdgcn_s_barrier()
#define WAIT_LGKM0()                                         \
  do {                                                       \
    asm volatile("s_waitcnt lgkmcnt(0)" ::: "memory");       \
    __builtin_amdgcn_sched_barrier(0);                       \
  } while (0)
#define WAIT_VM0()                                           \
  do {                                                       \
    asm volatile("s_waitcnt vmcnt(0)" ::: "memory");         \
  } while (0)

// ---------------------------------------------------------------------------
// 256x256-tile 8-wave GEMM, BK=64, double-buffered 128KiB LDS, T2 swizzle.
// C[r][c] = sum_k A[r][k]*B[c][k]  (both row-major, ld = DMODEL, K = DMODEL)
// MODE 0: write bf16 C. MODE 1: passA epilogue (exp, mask, E, Zpart).
// LDS tile layout: [256 rows][8 col8-groups of 16B], phys col8 = col8 ^ (row&7).
template <int MODE>
__global__ __launch_bounds__(512, 2)
void gemm256_kernel(const __hip_bfloat16* __restrict__ Aall,
                    const __hip_bfloat16* __restrict__ Ball,
                    __hip_bfloat16* __restrict__ Cout,
                    const int* __restrict__ mask,
                    const float* __restrict__ ub,
                    const float* __restrict__ vb,
                    __hip_bfloat16* __restrict__ E,
                    float* __restrict__ Zpart, int b0) {
  __shared__ __align__(16) char smem[131072];
  const int t = threadIdx.x, lane = t & 63, wid = t >> 6;
  const int wm = wid >> 2, wn = wid & 3;
  const int g = lane >> 4, l15 = lane & 15, l7 = lane & 7;

  const __hip_bfloat16 *Ab, *Bb;
  int kt2 = 0, qt2 = 0, cb = 0;
  if (MODE == 0) {
    Ab = Aall + (size_t)blockIdx.y * 256 * DMODEL;
    Bb = Ball + (size_t)blockIdx.x * 256 * DMODEL;
  } else {
    cb = blockIdx.y;
    kt2 = blockIdx.x >> 3;
    qt2 = blockIdx.x & 7;
    Ab = Aall + ((size_t)cb * SEQ + kt2 * 256) * DMODEL;
    Bb = Ball + ((size_t)cb * SEQ + qt2 * 256) * DMODEL;
  }

  char* bufA[2] = {smem, smem + 65536};
  char* bufB[2] = {smem + 32768, smem + 98304};

  // staging constants: thread t writes LDS linear L = it*8192 + t*16
  // -> row = h*128 + it*64 + (t>>3), phys col8 = t&7; source logical
  //    col8 = (t&7) ^ (row&7) = (t&7) ^ ((t>>3)&7)   (involution)
  const int srl = t >> 3;
  const int sc8 = (t & 7) ^ (srl & 7);
  // ds_read phys col8 for logical col8 = kk*4 + g on row with row&7 == l7&7
  const int pc8[2] = {g ^ l7, (4 + g) ^ l7};

  auto stage_mat = [&](const __hip_bfloat16* gs, char* dst, int kt) {
#pragma unroll
    for (int h = 0; h < 2; ++h)
#pragma unroll
      for (int it = 0; it < 2; ++it)
        gload16(gs + (size_t)(h * 128 + it * 64 + srl) * DMODEL + kt * 64 + sc8 * 8,
                dst + h * 16384 + it * 8192 + wid * 1024);
  };

  f32x4 acc[8][4];
#pragma unroll
  for (int m = 0; m < 8; ++m)
#pragma unroll
    for (int n = 0; n < 4; ++n) acc[m][n] = (f32x4){0.f, 0.f, 0.f, 0.f};
  short8 afr[2][4];      // [kk][m]  current mh quadrant
  short8 bfr[2][2][2];   // [nh][kk][n]  whole tile

#define LDA_Q(MH)                                                           \
  { _Pragma("unroll") for (int m = 0; m < 4; ++m) {                         \
      const int row = wm * 128 + ((MH) * 4 + m) * 16 + l15;                 \
      afr[0][m] = *(const short8*)(At + row * 128 + pc8[0] * 16);           \
      afr[1][m] = *(const short8*)(At + row * 128 + pc8[1] * 16);           \
    } }
#define LDB_Q(NH)                                                           \
  { _Pragma("unroll") for (int n = 0; n < 2; ++n) {                         \
      const int row = wn * 64 + ((NH) * 2 + n) * 16 + l15;                  \
      bfr[NH][0][n] = *(const short8*)(Bt + row * 128 + pc8[0] * 16);       \
      bfr[NH][1][n] = *(const short8*)(Bt + row * 128 + pc8[1] * 16);       \
    } }
#define MFMA_Q(MH, NH)                                                      \
  { __builtin_amdgcn_s_setprio(1);                                          \
    _Pragma("unroll") for (int kk = 0; kk < 2; ++kk)                        \
    _Pragma("unroll") for (int m = 0; m < 4; ++m)                           \
    _Pragma("unroll") for (int n = 0; n < 2; ++n)                           \
      acc[(MH)*4+m][(NH)*2+n] = __builtin_amdgcn_mfma_f32_16x16x32_bf16(    \
          afr[kk][m], bfr[NH][kk][n], acc[(MH)*4+m][(NH)*2+n], 0, 0, 0);    \
    __builtin_amdgcn_s_setprio(0); }

  // prologue: tile 0 -> buf0
  stage_mat(Ab, bufA[0], 0);
  stage_mat(Bb, bufB[0], 0);
  WAIT_VM0();
  BAR();

  const char *At, *Bt;
#pragma unroll 1
  for (int i = 0; i < 8; ++i) {
    // ---- phases 1-4: compute tile 2i (buf0), stage tile 2i+1 -> buf1 ----
    At = bufA[0]; Bt = bufB[0];
    LDA_Q(0) LDB_Q(0)
    stage_mat(Ab, bufA[1], 2 * i + 1);
    BAR(); WAIT_LGKM0(); MFMA_Q(0, 0) BAR();
    LDB_Q(1)
    stage_mat(Bb, bufB[1], 2 * i + 1);
    BAR(); WAIT_LGKM0(); MFMA_Q(0, 1) BAR();
    LDA_Q(1)
    BAR(); WAIT_LGKM0(); MFMA_Q(1, 0) BAR();
    MFMA_Q(1, 1)            // regs only; covers the vmcnt drain below
    WAIT_VM0();             // tile 2i+1 fully landed (loads ~3 phases old)
    BAR();
    // ---- phases 5-8: compute tile 2i+1 (buf1), stage tile 2i+2 -> buf0 ----
    At = bufA[1]; Bt = bufB[1];
    LDA_Q(0) LDB_Q(0)
    if (i < 7) stage_mat(Ab, bufA[0], 2 * i + 2);
    BAR(); WAIT_LGKM0(); MFMA_Q(0, 0) BAR();
    LDB_Q(1)
    if (i < 7) stage_mat(Bb, bufB[0], 2 * i + 2);
    BAR(); WAIT_LGKM0(); MFMA_Q(0, 1) BAR();
    LDA_Q(1)
    BAR(); WAIT_LGKM0(); MFMA_Q(1, 0) BAR();
    MFMA_Q(1, 1)
    WAIT_VM0();
    BAR();
  }
#undef LDA_Q
#undef LDB_Q
#undef MFMA_Q

  if (MODE == 0) {
    const size_t rb = (size_t)blockIdx.y * 256 + wm * 128;
    const int colb = blockIdx.x * 256 + wn * 64;
#pragma unroll
    for (int mi = 0; mi < 8; ++mi)
#pragma unroll
      for (int n = 0; n < 4; ++n) {
        const int col = colb + n * 16 + l15;
        const size_t row0 = rb + mi * 16 + g * 4;
#pragma unroll
        for (int j = 0; j < 4; ++j)
          Cout[(row0 + j) * DMODEL + col] = __float2bfloat16(acc[mi][n][j]);
      }
  } else {
    const int b = b0 + cb;
    float uq[4];
#pragma unroll
    for (int n = 0; n < 4; ++n)
      uq[n] = ub[(size_t)cb * SEQ + qt2 * 256 + wn * 64 + n * 16 + l15];
    float zc[4] = {0.f, 0.f, 0.f, 0.f};
#pragma unroll
    for (int mi = 0; mi < 8; ++mi) {
      const int krow0 = kt2 * 256 + wm * 128 + mi * 16 + g * 4;
      const int4 mk4 = *(const int4*)&mask[(size_t)b * SEQ + krow0];
      const float4 v4 = *(const float4*)&vb[(size_t)cb * SEQ + krow0];
#pragma unroll
      for (int j = 0; j < 4; ++j) {
        const int km = (j == 0) ? mk4.x : (j == 1) ? mk4.y : (j == 2) ? mk4.z : mk4.w;
        const float vj = (j == 0) ? v4.x : (j == 1) ? v4.y : (j == 2) ? v4.z : v4.w;
        __hip_bfloat16* Erow =
            E + ((size_t)cb * SEQ + krow0 + j) * SEQ + qt2 * 256 + wn * 64;
#pragma unroll
        for (int n = 0; n < 4; ++n) {
          const float e =
              km ? __expf((acc[mi][n][j] + uq[n] + vj) * 0.03125f) : 0.f;
          zc[n] += e;
          Erow[n * 16 + l15] = __float2bfloat16(e);
        }
      }
    }
#pragma unroll
    for (int n = 0; n < 4; ++n) {
      float v = zc[n];
      v += __shfl_xor(v, 16);
      v += __shfl_xor(v, 32);
      zc[n] = v;
    }
    float* red = (float*)smem;  // [2][256]; tiles dead, per-wave slices disjoint
    if (lane < 16) {
#pragma unroll
      for (int n = 0; n < 4; ++n)
        red[wm * 256 + wn * 64 + n * 16 + lane] = zc[n];
    }
    __syncthreads();
    if (t < 256)
      Zpart[((size_t)cb * 8 + kt2) * SEQ + qt2 * 256 + t] = red[t] + red[256 + t];
  }
}

// ---------------------------------------------------------------------------
// fp32 -> bf16 bulk convert (8 elems/thread/iter)
__global__ void cvt_bf16_kernel(const float* __restrict__ in,
                                __hip_bfloat16* __restrict__ outp, long n8) {
  long i = (long)blockIdx.x * 256 + threadIdx.x;
  const long stride = (long)gridDim.x * 256;
  for (; i < n8; i += stride) {
    const float4* p = (const float4*)in + i * 2;
    float4 v0 = p[0], v1 = p[1];
    union { __hip_bfloat16 h[8]; short8 v; } u;
    u.h[0] = __float2bfloat16(v0.x); u.h[1] = __float2bfloat16(v0.y);
    u.h[2] = __float2bfloat16(v0.z); u.h[3] = __float2bfloat16(v0.w);
    u.h[4] = __float2bfloat16(v1.x); u.h[5] = __float2bfloat16(v1.y);
    u.h[6] = __float2bfloat16(v1.z); u.h[7] = __float2bfloat16(v1.w);
    ((short8*)outp)[i] = u.v;
  }
}

// fp32 [DMODEL][DMODEL] -> bf16 transposed
__global__ void transpose_cvt_kernel(const float* __restrict__ in,
                                     __hip_bfloat16* __restrict__ outp) {
  __shared__ float tile[32][33];
  const int bx = blockIdx.x, by = blockIdx.y;
  const int tx = threadIdx.x & 31, ty = threadIdx.x >> 5;  // 32 x 8
#pragma unroll
  for (int r = 0; r < 32; r += 8)
    tile[ty + r][tx] = in[(size_t)(by * 32 + ty + r) * DMODEL + bx * 32 + tx];
  __syncthreads();
#pragma unroll
  for (int r = 0; r < 32; r += 8)
    outp[(size_t)(bx * 32 + ty + r) * DMODEL + by * 32 + tx] =
        __float2bfloat16(tile[tx][ty + r]);
}

// t1[d] = sum_e Wq[e][d]*bk[e], t2[d] = sum_e Wk[e][d]*bq[e], c = bq.bk
__global__ __launch_bounds__(256)
void prep_vec_kernel(const __hip_bfloat16* __restrict__ WqT,
                     const __hip_bfloat16* __restrict__ WkT,
                     const float* __restrict__ bq, const float* __restrict__ bk,
                     float* __restrict__ t1, float* __restrict__ t2,
                     float* __restrict__ cscal) {
  const int wave = threadIdx.x >> 6, lane = threadIdx.x & 63;
  if (blockIdx.x == 256) {
    if (wave != 0) return;
    float v = 0.f;
#pragma unroll
    for (int it = 0; it < 16; ++it) {
      const int i = it * 64 + lane;
      v += bq[i] * bk[i];
    }
    v += __shfl_down(v, 32); v += __shfl_down(v, 16); v += __shfl_down(v, 8);
    v += __shfl_down(v, 4);  v += __shfl_down(v, 2);  v += __shfl_down(v, 1);
    if (lane == 0) *cscal = v;
    return;
  }
  const int d = blockIdx.x * 4 + wave;
  const short8* qr = (const short8*)(WqT + (size_t)d * DMODEL);
  const short8* kr = (const short8*)(WkT + (size_t)d * DMODEL);
  float a1 = 0.f, a2 = 0.f;
#pragma unroll
  for (int h = 0; h < 2; ++h) {
    const short8 qv = qr[lane * 2 + h];
    const short8 kv = kr[lane * 2 + h];
    const int e0 = lane * 16 + h * 8;
#pragma unroll
    for (int i = 0; i < 8; ++i) {
      a1 += bf2f(qv[i]) * bk[e0 + i];
      a2 += bf2f(kv[i]) * bq[e0 + i];
    }
  }
  a1 += __shfl_down(a1, 32); a1 += __shfl_down(a1, 16); a1 += __shfl_down(a1, 8);
  a1 += __shfl_down(a1, 4);  a1 += __shfl_down(a1, 2);  a1 += __shfl_down(a1, 1);
  a2 += __shfl_down(a2, 32); a2 += __shfl_down(a2, 16); a2 += __shfl_down(a2, 8);
  a2 += __shfl_down(a2, 4);  a2 += __shfl_down(a2, 2);  a2 += __shfl_down(a2, 1);
  if (lane == 0) { t1[d] = a1; t2[d] = a2; }
}

// u[row] = x_bf[row].t1 + c ; v[row] = x_bf[row].t2
__global__ __launch_bounds__(256)
void uv_kernel(const __hip_bfloat16* __restrict__ x_bf,
               const float* __restrict__ t1, const float* __restrict__ t2,
               const float* __restrict__ cscal,
               float* __restrict__ ub, float* __restrict__ vb) {
  const int wave = threadIdx.x >> 6, lane = threadIdx.x & 63;
  const long row = (long)blockIdx.x * 4 + wave;
  const short8* xp = (const short8*)(x_bf + (size_t)row * DMODEL);
  float a1 = 0.f, a2 = 0.f;
#pragma unroll
  for (int h = 0; h < 2; ++h) {
    const short8 xv = xp[lane * 2 + h];
    const int d0 = lane * 16 + h * 8;
#pragma unroll
    for (int i = 0; i < 8; ++i) {
      const float xf = bf2f(xv[i]);
      a1 += xf * t1[d0 + i];
      a2 += xf * t2[d0 + i];
    }
  }
  a1 += __shfl_down(a1, 32); a1 += __shfl_down(a1, 16); a1 += __shfl_down(a1, 8);
  a1 += __shfl_down(a1, 4);  a1 += __shfl_down(a1, 2);  a1 += __shfl_down(a1, 1);
  a2 += __shfl_down(a2, 32); a2 += __shfl_down(a2, 16); a2 += __shfl_down(a2, 8);
  a2 += __shfl_down(a2, 4);  a2 += __shfl_down(a2, 2);  a2 += __shfl_down(a2, 1);
  if (lane == 0) { ub[row] = a1 + *cscal; vb[row] = a2; }
}

// rZ[b][q] = 1 / sum_{kt2<8} Zpart[b][kt2][q]  (0 if empty)
__global__ void zinv_kernel(const float* __restrict__ Zpart,
                            float* __restrict__ rZ, int n) {
  const int idx = blockIdx.x * 256 + threadIdx.x;
  if (idx >= n) return;
  const int cb = idx >> 11, q = idx & (SEQ - 1);
  float z = 0.f;
#pragma unroll
  for (int kt = 0; kt < 8; ++kt)
    z += Zpart[((size_t)cb * 8 + kt) * SEQ + q];
  rZ[(size_t)cb * SEQ + q] = (z > 0.f) ? (1.f / z) : 0.f;
}

// passB: w[k] = sum_q E[k][q] * rZ[q]
__global__ __launch_bounds__(256)
void passB_kernel(const __hip_bfloat16* __restrict__ E,
                  const float* __restrict__ rZ,
                  float* __restrict__ wout) {
  const int t = threadIdx.x, lane = t & 63, wave = t >> 6;
  const int cb = blockIdx.y;
  float4 rzv[4][2];
#pragma unroll
  for (int it = 0; it < 4; ++it) {
    const float4* p = (const float4*)(rZ + (size_t)cb * SEQ + it * 512 + lane * 8);
    rzv[it][0] = p[0];
    rzv[it][1] = p[1];
  }
  const int kbase = blockIdx.x * 16 + wave * 4;
#pragma unroll
  for (int r = 0; r < 4; ++r) {
    const int k = kbase + r;
    const short8* Ep = (const short8*)(E + ((size_t)cb * SEQ + k) * SEQ);
    float s = 0.f;
#pragma unroll
    for (int it = 0; it < 4; ++it) {
      const short8 v = Ep[it * 64 + lane];
      const float* rz = (const float*)&rzv[it][0];
#pragma unroll
      for (int e = 0; e < 8; ++e) s += bf2f(v[e]) * rz[e];
    }
    s += __shfl_down(s, 32); s += __shfl_down(s, 16); s += __shfl_down(s, 8);
    s += __shfl_down(s, 4);  s += __shfl_down(s, 2);  s += __shfl_down(s, 1);
    if (lane == 0) wout[(size_t)cb * SEQ + k] = s;
  }
}

// sumw_all[b] = sum_k w[k]
__global__ void sumw_kernel(const float* __restrict__ w,
                            float* __restrict__ sumw_all, int b0) {
  __shared__ float sred[4];
  const int t = threadIdx.x, lane = t & 63, wave = t >> 6;
  const int cb = blockIdx.x;
  float v = 0.f;
  for (int k = t; k < SEQ; k += 256) v += w[(size_t)cb * SEQ + k];
  v += __shfl_down(v, 32); v += __shfl_down(v, 16); v += __shfl_down(v, 8);
  v += __shfl_down(v, 4);  v += __shfl_down(v, 2);  v += __shfl_down(v, 1);
  if (lane == 0) sred[wave] = v;
  __syncthreads();
  if (t == 0) sumw_all[b0 + cb] = sred[0] + sred[1] + sred[2] + sred[3];
}

// wxp[kq][b][d] = sum_{k in chunk kq} w[k] * x_bf[b][k][d]
__global__ void wxpart_kernel(const __hip_bfloat16* __restrict__ x_bf,
                              const float* __restrict__ w,
                              float* __restrict__ wxp, int b0) {
  const int dt = blockIdx.x, cb = blockIdx.y, kq = blockIdx.z;
  const int b = b0 + cb;
  const int dp = dt * 256 + threadIdx.x;
  const __hip_bfloat16* xb =
      x_bf + ((size_t)cb * SEQ + (size_t)kq * (SEQ / KSPLIT)) * DMODEL;
  const float* wb = w + (size_t)cb * SEQ + (size_t)kq * (SEQ / KSPLIT);
  float a0 = 0.f, a1 = 0.f;
#pragma unroll 4
  for (int k = 0; k < SEQ / KSPLIT; ++k) {
    const float wk = wb[k];
    const uint32_t pv = *(const uint32_t*)(xb + (size_t)k * DMODEL + dp * 2);
    a0 += wk * bf2f((short)(pv & 0xffff));
    a1 += wk * bf2f((short)(pv >> 16));
  }
  float2* o = (float2*)&wxp[((size_t)kq * NBATCH + b) * DMODEL + dp * 2];
  *o = make_float2(a0, a1);
}

// out[b][e] = ( sum_d (sum_kq wxp[kq][b][d]) * Wv[e][d] + sumw[b]*bv[e] ) / SEQ
__global__ void final_kernel(const float* __restrict__ wxp,
                             const float* __restrict__ sumw_all,
                             const float* __restrict__ Wv,
                             const float* __restrict__ bv,
                             float* __restrict__ out) {
  const int b = blockIdx.y, eg = blockIdx.x;
  const int wave = threadIdx.x >> 6, lane = threadIdx.x & 63;
  const int e = eg * 4 + wave;
  float acc = 0.f;
  for (int d = lane; d < DMODEL; d += 64) {
    float wx = 0.f;
#pragma unroll
    for (int kq = 0; kq < KSPLIT; ++kq)
      wx += wxp[((size_t)kq * NBATCH + b) * DMODEL + d];
    acc += wx * Wv[(size_t)e * DMODEL + d];
  }
  acc += __shfl_down(acc, 32); acc += __shfl_down(acc, 16);
  acc += __shfl_down(acc, 8);  acc += __shfl_down(acc, 4);
  acc += __shfl_down(acc, 2);  acc += __shfl_down(acc, 1);
  if (lane == 0)
    out[(size_t)b * DMODEL + e] =
        (acc + sumw_all[b] * bv[e]) * (1.f / (float)SEQ);
}

// ---------------------------------------------------------------------------
extern "C" void kernel_launch(void* const* d_in, const int* in_sizes, int n_in,
                              void* d_out, int out_size, void* d_ws, size_t ws_size,
                              hipStream_t stream) {
  const float* x  = (const float*)d_in[0];
  const int* mask = (const int*)d_in[1];
  const float* Wq = (const float*)d_in[2];
  const float* bq = (const float*)d_in[3];
  const float* Wk = (const float*)d_in[4];
  const float* bk = (const float*)d_in[5];
  const float* Wv = (const float*)d_in[6];
  const float* bv = (const float*)d_in[7];
  float* out = (float*)d_out;

  char* ws = (char*)d_ws;
  size_t off = 0;
  auto alloc = [&](size_t bytes) -> void* {
    void* p = ws + off;
    off += (bytes + 255) & ~(size_t)255;
    return p;
  };
  // ---- persistent region ----
  __hip_bfloat16* Mt_bf = (__hip_bfloat16*)alloc((size_t)DMODEL * DMODEL * 2);
  float* wxp      = (float*)alloc((size_t)KSPLIT * NBATCH * DMODEL * 4);
  float* sumw_all = (float*)alloc((size_t)NBATCH * 4);
  float* t1       = (float*)alloc((size_t)DMODEL * 4);
  float* t2       = (float*)alloc((size_t)DMODEL * 4);
  float* cscal    = (float*)alloc(256);
  const size_t fixed = off;

  // transient W^T buffers aliased over the chunk region (consumed before cvt)
  __hip_bfloat16* WqT_bf = (__hip_bfloat16*)(ws + fixed);
  __hip_bfloat16* WkT_bf =
      (__hip_bfloat16*)(ws + fixed + (size_t)DMODEL * DMODEL * 2);

  // ---- per-chunk region ----
  const size_t per_batch = (size_t)SEQ * DMODEL * 2      // x_bf
                         + (size_t)SEQ * DMODEL * 2      // Y
                         + (size_t)SEQ * SEQ * 2         // E
                         + (size_t)16 * SEQ * 4          // Zpart (oversized)
                         + (size_t)4 * SEQ * 4 + 8 * 256;
  long avail = (long)ws_size - (long)fixed;
  int NB = (int)(avail / (long)per_batch);
  if (NB < 1) NB = 1;
  if (NB > NBATCH) NB = NBATCH;
  __hip_bfloat16* x_bf = (__hip_bfloat16*)alloc((size_t)NB * SEQ * DMODEL * 2);
  __hip_bfloat16* Yb   = (__hip_bfloat16*)alloc((size_t)NB * SEQ * DMODEL * 2);
  __hip_bfloat16* Ebuf = (__hip_bfloat16*)alloc((size_t)NB * SEQ * SEQ * 2);
  float* Zpart = (float*)alloc((size_t)NB * 16 * SEQ * 4);
  float* rZ    = (float*)alloc((size_t)NB * SEQ * 4);
  float* wbuf  = (float*)alloc((size_t)NB * SEQ * 4);
  float* ub    = (float*)alloc((size_t)NB * SEQ * 4);
  float* vb    = (float*)alloc((size_t)NB * SEQ * 4);

  // ---- one-off prep ----
  transpose_cvt_kernel<<<dim3(32, 32), dim3(256), 0, stream>>>(Wq, WqT_bf);
  transpose_cvt_kernel<<<dim3(32, 32), dim3(256), 0, stream>>>(Wk, WkT_bf);
  // Mt[d'][d] = sum_e WkT[d'][e]*WqT[d][e]
  gemm256_kernel<0><<<dim3(4, 4), dim3(512), 0, stream>>>(
      WkT_bf, WqT_bf, Mt_bf, nullptr, nullptr, nullptr, nullptr, nullptr, 0);
  prep_vec_kernel<<<dim3(257), dim3(256), 0, stream>>>(
      WqT_bf, WkT_bf, bq, bk, t1, t2, cscal);

  for (int b0 = 0; b0 < NBATCH; b0 += NB) {
    const int nb = (NBATCH - b0 < NB) ? (NBATCH - b0) : NB;
    const long n8 = (long)nb * SEQ * DMODEL / 8;
    cvt_bf16_kernel<<<dim3(2048), dim3(256), 0, stream>>>(
        x + (size_t)b0 * SEQ * DMODEL, x_bf, n8);
    // Y[q][d'] = sum_d x[q][d] * Mt[d'][d]
    gemm256_kernel<0><<<dim3(4, nb * 8), dim3(512), 0, stream>>>(
        x_bf, Mt_bf, Yb, nullptr, nullptr, nullptr, nullptr, nullptr, 0);
    uv_kernel<<<dim3(nb * SEQ / 4), dim3(256), 0, stream>>>(
        x_bf, t1, t2, cscal, ub, vb);
    // S^T tiles + exp + Zpart
    gemm256_kernel<1><<<dim3(64, nb), dim3(512), 0, stream>>>(
        x_bf, Yb, nullptr, mask, ub, vb, Ebuf, Zpart, b0);
    zinv_kernel<<<dim3((nb * SEQ + 255) / 256), dim3(256), 0, stream>>>(
        Zpart, rZ, nb * SEQ);
    passB_kernel<<<dim3(SEQ / 16, nb), dim3(256), 0, stream>>>(Ebuf, rZ, wbuf);
    sumw_kernel<<<dim3(nb), dim3(256), 0, stream>>>(wbuf, sumw_all, b0);
    wxpart_kernel<<<dim3(DMODEL / 512, nb, KSPLIT), dim3(256), 0, stream>>>(
        x_bf, wbuf, wxp, b0);
  }
  final_kernel<<<dim3(DMODEL / 4, NBATCH), dim3(256), 0, stream>>>(
      wxp, sumw_all, Wv, bv, out);
}